// Round 1
// baseline (1543.452 us; speedup 1.0000x reference)
//
#include <hip/hip_runtime.h>
#include <math.h>

#define NB   8
#define NC   16384
#define INV  64
#define HID  128
#define OUTV 64
#define ENG  128
#define G3   384

// ---- workspace float offsets ----
#define WS_AABS   0          // 8
#define WS_XB     8          // 8*64
#define WS_BASEA  520        // 8*128
#define WS_BASEG  1544       // 8*128
#define WS_BOUT   2568       // 64
#define WS_W1AT   2632       // 128*128  (k-major, h-part of eaW1)
#define WS_W1GT   19016      // 128*128
#define WS_W2AT   35400      // 128*64
#define WS_W2GT   43592      // 128*64
#define WS_WIHT   51784      // 65*384
#define WS_WHHT   76744      // 128*384
#define WS_CO     125896     // 16384*64
#define WS_AVGT   1174472    // 16384
#define WS_FPART  1190856    // 1024*8*128
#define WS_FMEAN  2239432    // 8*8*128
#define WS_GLOB   2247624    // 8*128
#define WS_HPART  2248648    // 1024*128
#define WS_INTERF 2379720    // 128

__global__ __launch_bounds__(256) void k0_prep(
    const float* __restrict__ x, const float* __restrict__ noise,
    const float* __restrict__ amps,
    const float* __restrict__ eaW1, const float* __restrict__ eaB1,
    const float* __restrict__ eaB2,
    const float* __restrict__ egW1, const float* __restrict__ egB1,
    const float* __restrict__ egB2,
    const float* __restrict__ eaW2, const float* __restrict__ egW2,
    const float* __restrict__ gWih, const float* __restrict__ gWhh,
    float* __restrict__ ws)
{
    int t = threadIdx.x;
    if (t == 0) {
        float s = 0.f;
        for (int b = 0; b < NB; b++) s += fabsf(amps[b]);
        s += 1e-8f;
        for (int b = 0; b < NB; b++) ws[WS_AABS + b] = fabsf(amps[b]) / s;
    }
    // xb[b][k] = x[k] + noise[b][k] * 0.05*(b+1)
    for (int i = t; i < NB * INV; i += 256) {
        int b = i >> 6, k = i & 63;
        ws[WS_XB + i] = x[k] + noise[b * INV + k] * (0.05f * (float)(b + 1));
    }
    __syncthreads();
    // per-branch layer1 bias: baseA[b][e] = eaB1[e] + sum_k xb[b][k]*eaW1[e][k]
    for (int i = t; i < NB * ENG; i += 256) {
        int b = i >> 7, e = i & 127;
        float sa = eaB1[e], sg = egB1[e];
        for (int k = 0; k < INV; k++) {
            float xv = ws[WS_XB + b * INV + k];
            sa += xv * eaW1[e * 192 + k];
            sg += xv * egW1[e * 192 + k];
        }
        ws[WS_BASEA + i] = sa;
        ws[WS_BASEG + i] = sg;
    }
    for (int d = t; d < OUTV; d += 256) ws[WS_BOUT + d] = eaB2[d] - egB2[d];
    // k-major transposes
    for (int i = t; i < 128 * 128; i += 256) {
        int k = i >> 7, e = i & 127;
        ws[WS_W1AT + k * 128 + e] = eaW1[e * 192 + 64 + k];
        ws[WS_W1GT + k * 128 + e] = egW1[e * 192 + 64 + k];
    }
    for (int i = t; i < 128 * 64; i += 256) {
        int e = i >> 6, d = i & 63;
        ws[WS_W2AT + e * 64 + d] = eaW2[d * 128 + e];
        ws[WS_W2GT + e * 64 + d] = egW2[d * 128 + e];
    }
    for (int i = t; i < 65 * G3; i += 256) {
        int d = i / G3, r = i % G3;
        ws[WS_WIHT + d * G3 + r] = gWih[r * 65 + d];
    }
    for (int i = t; i < 128 * G3; i += 256) {
        int e = i / G3, r = i % G3;
        ws[WS_WHHT + e * G3 + r] = gWhh[r * 128 + e];
    }
}

// main cell kernel: 1024 blocks x 256 threads, 16 cells/block, loops 8 branches
__global__ __launch_bounds__(256) void k1_cells(
    const float* __restrict__ hiddens,
    const float* __restrict__ gbih, const float* __restrict__ gbhh,
    float* __restrict__ newh, float* __restrict__ ws)
{
    __shared__ float hs[16][129];
    __shared__ float ha[16][128];
    __shared__ float hg[16][128];
    __shared__ float outb[16][64];
    __shared__ float co[16][64];
    __shared__ float ts_s[16];
    __shared__ float tsum[16];
    __shared__ float fp2[2][128];

    const int t  = threadIdx.x;
    const int n0 = blockIdx.x * 16;

    for (int idx = t; idx < 16 * 64; idx += 256) co[idx >> 6][idx & 63] = 0.f;
    if (t < 16) tsum[t] = 0.f;
    __syncthreads();

    for (int b = 0; b < NB; b++) {
        // stage h rows
        for (int idx = t; idx < 16 * 128; idx += 256) {
            int c = idx >> 7, k = idx & 127;
            hs[c][k] = hiddens[((size_t)(b * NC + n0 + c)) * HID + k];
        }
        __syncthreads();
        // layer1: a & g fused
        {
            int e = t & 127, ch = t >> 7;
            float acca[8], accg[8];
            float ba = ws[WS_BASEA + b * 128 + e];
            float bg = ws[WS_BASEG + b * 128 + e];
#pragma unroll
            for (int i = 0; i < 8; i++) { acca[i] = ba; accg[i] = bg; }
            for (int k = 0; k < 128; k++) {
                float wa = ws[WS_W1AT + k * 128 + e];
                float wg = ws[WS_W1GT + k * 128 + e];
#pragma unroll
                for (int i = 0; i < 8; i++) {
                    float hv = hs[ch * 8 + i][k];
                    acca[i] += hv * wa;
                    accg[i] += hv * wg;
                }
            }
#pragma unroll
            for (int i = 0; i < 8; i++) {
                ha[ch * 8 + i][e] = fmaxf(acca[i], 0.f);
                hg[ch * 8 + i][e] = fmaxf(accg[i], 0.f);
            }
        }
        __syncthreads();
        // layer2: out = a - g
        {
            int d = t & 63, cq = t >> 6;
            float acc[4];
            float bo = ws[WS_BOUT + d];
#pragma unroll
            for (int i = 0; i < 4; i++) acc[i] = bo;
            for (int e = 0; e < 128; e++) {
                float wa = ws[WS_W2AT + e * 64 + d];
                float wg = ws[WS_W2GT + e * 64 + d];
#pragma unroll
                for (int i = 0; i < 4; i++) {
                    int c = cq * 4 + i;
                    acc[i] += ha[c][e] * wa - hg[c][e] * wg;
                }
            }
#pragma unroll
            for (int i = 0; i < 4; i++) outb[cq * 4 + i][d] = acc[i];
        }
        __syncthreads();
        // tension
        if (t < 16) {
            float s = 0.f;
            for (int d = 0; d < 64; d++) { float v = outb[t][d]; s += v * v; }
            s *= (1.f / 64.f);
            ts_s[t] = s;
            tsum[t] += s;
        }
        __syncthreads();
        // amplitude-weighted accumulate
        {
            float ab = ws[WS_AABS + b];
            for (int idx = t; idx < 16 * 64; idx += 256) {
                int c = idx >> 6, d = idx & 63;
                co[c][d] += ab * outb[c][d];
            }
        }
        __syncthreads();
        // GRU combine: gi (from out+tension) + gh (from h)
        {
            int h = t & 127, ch = t >> 7;
            float gir[8], giz[8], gin[8];
            float bi_r = gbih[h], bi_z = gbih[128 + h], bi_n = gbih[256 + h];
#pragma unroll
            for (int i = 0; i < 8; i++) { gir[i] = bi_r; giz[i] = bi_z; gin[i] = bi_n; }
            for (int d = 0; d < 64; d++) {
                float wr = ws[WS_WIHT + d * G3 + h];
                float wz = ws[WS_WIHT + d * G3 + 128 + h];
                float wn = ws[WS_WIHT + d * G3 + 256 + h];
#pragma unroll
                for (int i = 0; i < 8; i++) {
                    float od = outb[ch * 8 + i][d];
                    gir[i] += od * wr; giz[i] += od * wz; gin[i] += od * wn;
                }
            }
            {
                float wr = ws[WS_WIHT + 64 * G3 + h];
                float wz = ws[WS_WIHT + 64 * G3 + 128 + h];
                float wn = ws[WS_WIHT + 64 * G3 + 256 + h];
#pragma unroll
                for (int i = 0; i < 8; i++) {
                    float tv = ts_s[ch * 8 + i];
                    gir[i] += tv * wr; giz[i] += tv * wz; gin[i] += tv * wn;
                }
            }
            float ghr[8], ghz[8], ghn[8];
            float bh_r = gbhh[h], bh_z = gbhh[128 + h], bh_n = gbhh[256 + h];
#pragma unroll
            for (int i = 0; i < 8; i++) { ghr[i] = bh_r; ghz[i] = bh_z; ghn[i] = bh_n; }
            for (int e = 0; e < 128; e++) {
                float wr = ws[WS_WHHT + e * G3 + h];
                float wz = ws[WS_WHHT + e * G3 + 128 + h];
                float wn = ws[WS_WHHT + e * G3 + 256 + h];
#pragma unroll
                for (int i = 0; i < 8; i++) {
                    float hv = hs[ch * 8 + i][e];
                    ghr[i] += hv * wr; ghz[i] += hv * wz; ghn[i] += hv * wn;
                }
            }
            float fls = 0.f;
#pragma unroll
            for (int i = 0; i < 8; i++) {
                int c = ch * 8 + i;
                float r = 1.f / (1.f + expf(-(gir[i] + ghr[i])));
                float z = 1.f / (1.f + expf(-(giz[i] + ghz[i])));
                float nn = tanhf(gin[i] + r * ghn[i]);
                float nh = (1.f - z) * nn + z * hs[c][h];
                newh[((size_t)(b * NC + n0 + c)) * HID + h] = nh;
                fls += nh;
            }
            fp2[ch][h] = fls;
        }
        __syncthreads();
        if (t < 128)
            ws[WS_FPART + (size_t)blockIdx.x * 1024 + b * 128 + t] = fp2[0][t] + fp2[1][t];
        __syncthreads();
    }
    // epilogue
    for (int idx = t; idx < 16 * 64; idx += 256) {
        int c = idx >> 6, d = idx & 63;
        ws[WS_CO + (size_t)(n0 + c) * 64 + d] = co[c][d];
    }
    if (t < 16) ws[WS_AVGT + n0 + t] = tsum[t] * 0.125f;
}

__global__ __launch_bounds__(128) void k2_fmean(float* __restrict__ ws)
{
    int bf = blockIdx.x; int b = bf >> 3, f = bf & 7; int h = threadIdx.x;
    float s = 0.f;
    for (int j = 0; j < 128; j++)
        s += ws[WS_FPART + (size_t)(f * 128 + j) * 1024 + b * 128 + h];
    ws[WS_FMEAN + (b * 8 + f) * 128 + h] = s * (1.f / 2048.f);
}

__global__ __launch_bounds__(1024) void k2_glob(float* __restrict__ ws)
{
    int t = threadIdx.x;
    int b = t >> 7, h = t & 127;
    float s = 0.f;
    for (int f = 0; f < 8; f++) s += ws[WS_FMEAN + (b * 8 + f) * 128 + h];
    ws[WS_GLOB + t] = s * 0.125f;
}

__global__ __launch_bounds__(1024) void ksoft(
    const float* __restrict__ ws, const float* __restrict__ headW,
    const float* __restrict__ headb, float* __restrict__ d_out)
{
    __shared__ float red[1024];
    __shared__ float comb[64];
    __shared__ float m_s, den_s;
    int t = threadIdx.x;
    float m = -3.4e38f;
    for (int n = t; n < NC; n += 1024) m = fmaxf(m, ws[WS_AVGT + n]);
    red[t] = m; __syncthreads();
    for (int s = 512; s > 0; s >>= 1) { if (t < s) red[t] = fmaxf(red[t], red[t + s]); __syncthreads(); }
    if (t == 0) m_s = red[0];
    __syncthreads();
    m = m_s;
    float se = 0.f, sa = 0.f;
    for (int n = t; n < NC; n += 1024) { float v = ws[WS_AVGT + n]; se += expf(v - m); sa += v; }
    red[t] = se; __syncthreads();
    for (int s = 512; s > 0; s >>= 1) { if (t < s) red[t] += red[t + s]; __syncthreads(); }
    if (t == 0) den_s = red[0];
    __syncthreads();
    red[t] = sa; __syncthreads();
    for (int s = 512; s > 0; s >>= 1) { if (t < s) red[t] += red[t + s]; __syncthreads(); }
    if (t == 0) d_out[64] = red[0] * (1.f / (float)NC);
    __syncthreads();
    int d = t & 63, q = t >> 6;   // 16 stripes
    float ca = 0.f;
    for (int n = q; n < NC; n += 16)
        ca += expf(ws[WS_AVGT + n] - m) * ws[WS_CO + (size_t)n * 64 + d];
    red[t] = ca; __syncthreads();
    if (t < 64) {
        float s = 0.f;
        for (int j = 0; j < 16; j++) s += red[t + 64 * j];
        comb[t] = s / den_s;
    }
    __syncthreads();
    if (t < 64) {
        float p = headb[t];
        for (int d2 = 0; d2 < 64; d2++) p += comb[d2] * headW[t * 64 + d2];
        d_out[t] = p;
    }
}

// faction sync + debate blend (in-place) + per-block hmean partials
__global__ __launch_bounds__(256) void k3_blend(
    float* __restrict__ newh, float* __restrict__ ws, const int* __restrict__ step)
{
    int blk = blockIdx.x;
    int b = blk >> 7;
    int cellbase = (blk & 127) * 128;
    int t = threadIdx.x;
    int h = t & 127, ch = t >> 7;
    bool debate = (step[0] > 5);
    float fls = 0.f;
    for (int i = 0; i < 64; i++) {
        int c = cellbase + ch + 2 * i;
        int f = c >> 11;
        size_t idx = ((size_t)b * NC + c) * HID + h;
        float v = newh[idx];
        v = 0.85f * v + 0.15f * ws[WS_FMEAN + (b * 8 + f) * 128 + h];
        if (debate && ((c & 2047) < 512))
            v = 0.85f * v + 0.15f * ws[WS_GLOB + b * 128 + h];
        newh[idx] = v;
        fls += v;
    }
    __shared__ float fp2[2][128];
    fp2[ch][h] = fls;
    __syncthreads();
    if (t < 128) ws[WS_HPART + (size_t)blk * 128 + t] = fp2[0][t] + fp2[1][t];
}

__global__ __launch_bounds__(128) void k4_interf(
    const float* __restrict__ mixW, const float* __restrict__ mixb, float* __restrict__ ws)
{
    int h = threadIdx.x;
    __shared__ float hm[1024];
    for (int j = h; j < 1024; j += 128) {
        int b = j >> 7, hh = j & 127;
        float s = 0.f;
        for (int k = 0; k < 128; k++)
            s += ws[WS_HPART + (size_t)(b * 128 + k) * 128 + hh];
        hm[j] = s * (1.f / (float)NC);
    }
    __syncthreads();
    float acc = mixb[h];
    for (int j = 0; j < 1024; j++) acc += hm[j] * mixW[h * 1024 + j];
    ws[WS_INTERF + h] = acc;
}

__global__ __launch_bounds__(256) void k5_apply(float* __restrict__ newh, const float* __restrict__ ws)
{
    size_t i = (size_t)blockIdx.x * 256 + threadIdx.x;
    if (i < (size_t)NC * HID) {
        int h = (int)(i & 127);
        newh[i] += 0.05f * ws[WS_INTERF + h];
    }
}

extern "C" void kernel_launch(void* const* d_in, const int* in_sizes, int n_in,
                              void* d_out, int out_size, void* d_ws, size_t ws_size,
                              hipStream_t stream)
{
    const float* x       = (const float*)d_in[0];
    const float* noise   = (const float*)d_in[1];
    const float* amps    = (const float*)d_in[2];
    const float* hiddens = (const float*)d_in[3];
    const float* eaW1    = (const float*)d_in[4];
    const float* eaB1    = (const float*)d_in[5];
    const float* eaW2    = (const float*)d_in[6];
    const float* eaB2    = (const float*)d_in[7];
    const float* egW1    = (const float*)d_in[8];
    const float* egB1    = (const float*)d_in[9];
    const float* egW2    = (const float*)d_in[10];
    const float* egB2    = (const float*)d_in[11];
    const float* gWih    = (const float*)d_in[12];
    const float* gWhh    = (const float*)d_in[13];
    const float* gbih    = (const float*)d_in[14];
    const float* gbhh    = (const float*)d_in[15];
    const float* headW   = (const float*)d_in[16];
    const float* headb   = (const float*)d_in[17];
    const float* mixW    = (const float*)d_in[18];
    const float* mixb    = (const float*)d_in[19];
    const int*   step    = (const int*)d_in[20];

    float* out  = (float*)d_out;
    float* newh = out + 65;           // [pred(64), avg_t_mean(1), newh(8*16384*128)]
    float* ws   = (float*)d_ws;

    k0_prep<<<1, 256, 0, stream>>>(x, noise, amps, eaW1, eaB1, eaB2,
                                   egW1, egB1, egB2, eaW2, egW2, gWih, gWhh, ws);
    k1_cells<<<1024, 256, 0, stream>>>(hiddens, gbih, gbhh, newh, ws);
    k2_fmean<<<64, 128, 0, stream>>>(ws);
    k2_glob<<<1, 1024, 0, stream>>>(ws);
    ksoft<<<1, 1024, 0, stream>>>(ws, headW, headb, out);
    k3_blend<<<1024, 256, 0, stream>>>(newh, ws, step);
    k4_interf<<<1, 128, 0, stream>>>(mixW, mixb, ws);
    k5_apply<<<8192, 256, 0, stream>>>(newh, ws);
}

// Round 2
// 701.716 us; speedup vs baseline: 2.1995x; 2.1995x over previous
//
#include <hip/hip_runtime.h>
#include <math.h>

#define NB   8
#define NCC  16384
#define HID  128

typedef __attribute__((ext_vector_type(8))) short short8;
typedef __attribute__((ext_vector_type(4))) float f32x4;

#define MFMA(a,b,c) __builtin_amdgcn_mfma_f32_16x16x32_bf16(a,b,c,0,0,0)

// ---- ws float offsets ----
#define WS_AABS   0
#define WS_BASE1  8
#define WS_BOUT   2056
#define WS_BSUMR  2120
#define WS_BSUMZ  2248
#define WS_BIHN   2376
#define WS_BHHN   2504
#define WS_W64    2632
#define WS_STAT   3016
#define WS_INTERF 3024
#define WS_FRAG   3152        // 61440 floats = 122880 bf16 frags
#define WS_TS     64592       // 8*16384
#define WS_AVGT   195664      // 16384
#define WS_CO     212048      // 16384*64
#define WS_FPART  1260624     // 8*256*128
#define WS_FMEAN  1522768     // 64*128
#define WS_GLOB   1530960     // 8*128
#define WS_PART2  1531984     // 256*64

// frag sub-offsets in shorts
#define FO_W1  0
#define FO_W2  32768
#define FO_WIH 49152
#define FO_WHH 73728

__device__ __forceinline__ unsigned short f2b(float f) {
    unsigned int u = __float_as_uint(f);
    unsigned int r = (u + 0x7fffu + ((u >> 16) & 1u)) >> 16;
    return (unsigned short)r;
}
__device__ __forceinline__ float b2f(unsigned short us) {
    return __uint_as_float(((unsigned int)us) << 16);
}
__device__ __forceinline__ float sigm(float x) {
    return __builtin_amdgcn_rcpf(1.f + __expf(-x));
}
__device__ __forceinline__ float tanh_fast(float x) {
    return 1.f - 2.f * __builtin_amdgcn_rcpf(__expf(2.f * x) + 1.f);
}

// ---------------- small prep: biases, xb-folded base, scalars ----------------
__global__ __launch_bounds__(256) void k0s(
    const float* __restrict__ x, const float* __restrict__ noise,
    const float* __restrict__ amps,
    const float* __restrict__ eaW1, const float* __restrict__ eaB1,
    const float* __restrict__ egW1, const float* __restrict__ egB1,
    const float* __restrict__ eaB2, const float* __restrict__ egB2,
    const float* __restrict__ gbih, const float* __restrict__ gbhh,
    const float* __restrict__ gWih, float* __restrict__ ws)
{
    __shared__ float xb[8][64];
    int t = threadIdx.x;
    for (int i = t; i < 512; i += 256) {
        int b = i >> 6, k = i & 63;
        xb[b][k] = x[k] + noise[b * 64 + k] * (0.05f * (float)(b + 1));
    }
    if (t == 0) {
        float s = 0.f;
        for (int b = 0; b < 8; b++) s += fabsf(amps[b]);
        s += 1e-8f;
        for (int b = 0; b < 8; b++) ws[WS_AABS + b] = fabsf(amps[b]) / s;
    }
    __syncthreads();
    for (int i = t; i < 2048; i += 256) {
        int b = i >> 8, n = i & 255;
        const float* Wp; float s;
        if (n < 128) { Wp = eaW1 + n * 192; s = eaB1[n]; }
        else         { Wp = egW1 + (n - 128) * 192; s = egB1[n - 128]; }
        for (int k = 0; k < 64; k++) s += xb[b][k] * Wp[k];
        ws[WS_BASE1 + i] = s;
    }
    if (t < 64) ws[WS_BOUT + t] = eaB2[t] - egB2[t];
    if (t < 128) {
        ws[WS_BSUMR + t] = gbih[t] + gbhh[t];
        ws[WS_BSUMZ + t] = gbih[128 + t] + gbhh[128 + t];
        ws[WS_BIHN + t]  = gbih[256 + t];
        ws[WS_BHHN + t]  = gbhh[256 + t];
    }
    for (int i = t; i < 384; i += 256) ws[WS_W64 + i] = gWih[i * 65 + 64];
}

// ---------------- weight -> MFMA B-fragment pre-swizzle (bf16) ----------------
// frag layout per matrix (K,N,KT=K/32): idx = (((nt*KT+kt)*64+l)*8+j)
// element: n = nt*16 + (l&15), k = kt*32 + ((l>>4)<<3) + j
__global__ __launch_bounds__(1024) void kfrag(
    const float* __restrict__ eaW1, const float* __restrict__ egW1,
    const float* __restrict__ eaW2, const float* __restrict__ egW2,
    const float* __restrict__ gWih, const float* __restrict__ gWhh,
    float* __restrict__ ws)
{
    int i = blockIdx.x * 1024 + threadIdx.x;
    if (i >= 122880) return;
    short* wsh = (short*)(ws + WS_FRAG);
    float v;
    if (i < 32768) {                       // W1: K=128, N=256 (a|g), KT=4
        int rel = i;
        int j = rel & 7, l = (rel >> 3) & 63, tk = rel >> 9;
        int kt = tk & 3, nt = tk >> 2;
        int n = nt * 16 + (l & 15), k = kt * 32 + ((l >> 4) << 3) + j;
        v = (n < 128) ? eaW1[n * 192 + 64 + k] : egW1[(n - 128) * 192 + 64 + k];
    } else if (i < 49152) {                // W2: K=256 ([A1|G1]), N=64, KT=8
        int rel = i - 32768;
        int j = rel & 7, l = (rel >> 3) & 63, tk = rel >> 9;
        int kt = tk & 7, nt = tk >> 3;
        int d = nt * 16 + (l & 15), k = kt * 32 + ((l >> 4) << 3) + j;
        v = (k < 128) ? eaW2[d * 128 + k] : -egW2[d * 128 + (k - 128)];
    } else if (i < 73728) {                // WIH: K=64, N=384, KT=2
        int rel = i - 49152;
        int j = rel & 7, l = (rel >> 3) & 63, tk = rel >> 9;
        int kt = tk & 1, nt = tk >> 1;
        int r = nt * 16 + (l & 15), k = kt * 32 + ((l >> 4) << 3) + j;
        v = gWih[r * 65 + k];
    } else {                               // WHH: K=128, N=384, KT=4
        int rel = i - 73728;
        int j = rel & 7, l = (rel >> 3) & 63, tk = rel >> 9;
        int kt = tk & 3, nt = tk >> 2;
        int r = nt * 16 + (l & 15), k = kt * 32 + ((l >> 4) << 3) + j;
        v = gWhh[r * 128 + k];
    }
    wsh[i] = (short)f2b(v);
}

// ---------------- main MFMA kernel: 256 blocks x 512 thr (8 waves), 64 cells, loop 8 branches
__global__ __launch_bounds__(512) void k1_cells(
    const float* __restrict__ hiddens, float* __restrict__ newh,
    float* __restrict__ ws)
{
    __shared__ char  hsb[64 * 256];    // bf16 [64][128] xor-swizzled
    __shared__ char  agb[64 * 512];    // bf16 [64][256] (relu a | relu g)
    __shared__ char  otb[64 * 128];    // bf16 [64][64]  (out)
    __shared__ float outf[64][68];     // f32 out, padded
    __shared__ float co_s[64][64];
    __shared__ float ts_s[64];
    __shared__ float fp[128];

    const int t    = threadIdx.x;
    const int lane = t & 63;
    const int w    = t >> 6;
    const int rh   = w >> 2;           // row half: 0/1 -> rows [rh*32, rh*32+32)
    const int nq   = w & 3;            // N quarter
    const int col  = lane & 15;
    const int kq   = lane >> 4;        // 0..3
    const int r0   = rh * 32;
    const int chunk = blockIdx.x;
    const int n0   = chunk * 64;

    const short* wsh  = (const short*)(ws + WS_FRAG);
    const short8* W1F  = (const short8*)(wsh + FO_W1);
    const short8* W2F  = (const short8*)(wsh + FO_W2);
    const short8* WIHF = (const short8*)(wsh + FO_WIH);
    const short8* WHHF = (const short8*)(wsh + FO_WHH);

    for (int i = t; i < 4096; i += 512) ((float*)co_s)[i] = 0.f;

    for (int b = 0; b < NB; b++) {
        if (t < 128) fp[t] = 0.f;
        // ---- stage hiddens -> bf16 LDS (swizzled) ----
        const float* hsrc = hiddens + ((size_t)(b * NCC + n0)) * HID;
#pragma unroll
        for (int p = 0; p < 2; p++) {
            int flat = (p * 512 + t) * 8;
            int row = flat >> 7;
            int cb  = (flat & 127) * 2;
            float4 u = *(const float4*)(hsrc + flat);
            float4 v = *(const float4*)(hsrc + flat + 4);
            unsigned int p0 = (unsigned)f2b(u.x) | ((unsigned)f2b(u.y) << 16);
            unsigned int p1 = (unsigned)f2b(u.z) | ((unsigned)f2b(u.w) << 16);
            unsigned int p2 = (unsigned)f2b(v.x) | ((unsigned)f2b(v.y) << 16);
            unsigned int p3 = (unsigned)f2b(v.z) | ((unsigned)f2b(v.w) << 16);
            uint4 pk = make_uint4(p0, p1, p2, p3);
            *(uint4*)(hsb + row * 256 + (cb ^ ((row & 7) << 4))) = pk;
        }
        __syncthreads();

        // ---- L1: [relu(a)|relu(g)] = relu(H @ W1^T + base1), 64x256, K=128 ----
        {
            short8 aH[2][4];
#pragma unroll
            for (int mt = 0; mt < 2; mt++)
#pragma unroll
                for (int ks = 0; ks < 4; ks++) {
                    int row = r0 + mt * 16 + col;
                    aH[mt][ks] = *(const short8*)(hsb + row * 256 +
                                   ((ks * 64 + (kq << 4)) ^ ((row & 7) << 4)));
                }
#pragma unroll
            for (int nti = 0; nti < 4; nti++) {
                int nt = nq * 4 + nti;
                f32x4 ac0 = {0.f, 0.f, 0.f, 0.f};
                f32x4 ac1 = {0.f, 0.f, 0.f, 0.f};
#pragma unroll
                for (int kt = 0; kt < 4; kt++) {
                    short8 bf = W1F[(nt * 4 + kt) * 64 + lane];
                    ac0 = MFMA(aH[0][kt], bf, ac0);
                    ac1 = MFMA(aH[1][kt], bf, ac1);
                }
                int n = nt * 16 + col;
                float bs = ws[WS_BASE1 + b * 256 + n];
#pragma unroll
                for (int mt = 0; mt < 2; mt++) {
                    f32x4 a = mt ? ac1 : ac0;
#pragma unroll
                    for (int j = 0; j < 4; j++) {
                        int row = r0 + mt * 16 + (kq << 2) + j;
                        float v = fmaxf(a[j] + bs, 0.f);
                        *(unsigned short*)(agb + row * 512 +
                            ((n * 2) ^ ((row & 7) << 4))) = f2b(v);
                    }
                }
            }
        }
        __syncthreads();

        // ---- L2: out = [A1|G1] @ [W2A;-W2G] + bout, 64x64, K=256 ----
        {
            int nt = nq;
            f32x4 ac0 = {0.f, 0.f, 0.f, 0.f};
            f32x4 ac1 = {0.f, 0.f, 0.f, 0.f};
#pragma unroll
            for (int kt = 0; kt < 8; kt++) {
                int kb = kt * 64 + (kq << 4);
                int ra = r0 + col, rb = r0 + 16 + col;
                short8 a0 = *(const short8*)(agb + ra * 512 + (kb ^ ((ra & 7) << 4)));
                short8 a1 = *(const short8*)(agb + rb * 512 + (kb ^ ((rb & 7) << 4)));
                short8 bf = W2F[(nt * 8 + kt) * 64 + lane];
                ac0 = MFMA(a0, bf, ac0);
                ac1 = MFMA(a1, bf, ac1);
            }
            int d = nt * 16 + col;
            float bo = ws[WS_BOUT + d];
#pragma unroll
            for (int mt = 0; mt < 2; mt++) {
                f32x4 a = mt ? ac1 : ac0;
#pragma unroll
                for (int j = 0; j < 4; j++) {
                    int row = r0 + mt * 16 + (kq << 2) + j;
                    float v = a[j] + bo;
                    outf[row][d] = v;
                    *(unsigned short*)(otb + row * 128 +
                        ((d * 2) ^ ((row & 7) << 4))) = f2b(v);
                }
            }
        }
        __syncthreads();

        // ---- tension, ts, co accumulate ----
        {
            int c = t >> 3, q = t & 7;
            float s = 0.f;
#pragma unroll
            for (int i = 0; i < 8; i++) { float v = outf[c][q * 8 + i]; s += v * v; }
            s += __shfl_xor(s, 1);
            s += __shfl_xor(s, 2);
            s += __shfl_xor(s, 4);
            if (q == 0) {
                float sv = s * (1.f / 64.f);
                ts_s[c] = sv;
                ws[WS_TS + (size_t)b * NCC + n0 + c] = sv;
            }
            float aab = ws[WS_AABS + b];
#pragma unroll
            for (int i = 0; i < 8; i++) {
                int e = t + 512 * i;
                int cc = e >> 6, dd = e & 63;
                co_s[cc][dd] += aab * outf[cc][dd];
            }
        }
        __syncthreads();

        // ---- GRU: gi (K=64 from out) + gh (K=128 from h) ----
        {
            float* nbase = newh + ((size_t)(b * NCC + n0)) * HID;
#pragma unroll
            for (int hgi = 0; hgi < 2; hgi++) {
                int hg = nq * 2 + hgi;
                f32x4 aR0 = {0.f,0.f,0.f,0.f}, aR1 = {0.f,0.f,0.f,0.f};
                f32x4 aZ0 = {0.f,0.f,0.f,0.f}, aZ1 = {0.f,0.f,0.f,0.f};
                f32x4 aI0 = {0.f,0.f,0.f,0.f}, aI1 = {0.f,0.f,0.f,0.f};
                f32x4 aN0 = {0.f,0.f,0.f,0.f}, aN1 = {0.f,0.f,0.f,0.f};
#pragma unroll
                for (int ks = 0; ks < 2; ks++) {
                    int kb = ks * 64 + (kq << 4);
                    int ra = r0 + col, rb = r0 + 16 + col;
                    short8 a0 = *(const short8*)(otb + ra * 128 + (kb ^ ((ra & 7) << 4)));
                    short8 a1 = *(const short8*)(otb + rb * 128 + (kb ^ ((rb & 7) << 4)));
                    short8 br = WIHF[(hg * 2 + ks) * 64 + lane];
                    short8 bz = WIHF[((hg + 8) * 2 + ks) * 64 + lane];
                    short8 bi = WIHF[((hg + 16) * 2 + ks) * 64 + lane];
                    aR0 = MFMA(a0, br, aR0); aR1 = MFMA(a1, br, aR1);
                    aZ0 = MFMA(a0, bz, aZ0); aZ1 = MFMA(a1, bz, aZ1);
                    aI0 = MFMA(a0, bi, aI0); aI1 = MFMA(a1, bi, aI1);
                }
#pragma unroll
                for (int ks = 0; ks < 4; ks++) {
                    int kb = ks * 64 + (kq << 4);
                    int ra = r0 + col, rb = r0 + 16 + col;
                    short8 a0 = *(const short8*)(hsb + ra * 256 + (kb ^ ((ra & 7) << 4)));
                    short8 a1 = *(const short8*)(hsb + rb * 256 + (kb ^ ((rb & 7) << 4)));
                    short8 br = WHHF[(hg * 4 + ks) * 64 + lane];
                    short8 bz = WHHF[((hg + 8) * 4 + ks) * 64 + lane];
                    short8 bn = WHHF[((hg + 16) * 4 + ks) * 64 + lane];
                    aR0 = MFMA(a0, br, aR0); aR1 = MFMA(a1, br, aR1);
                    aZ0 = MFMA(a0, bz, aZ0); aZ1 = MFMA(a1, bz, aZ1);
                    aN0 = MFMA(a0, bn, aN0); aN1 = MFMA(a1, bn, aN1);
                }
                int h = hg * 16 + col;
                float bsr = ws[WS_BSUMR + h], bsz = ws[WS_BSUMZ + h];
                float bin = ws[WS_BIHN + h], bhn = ws[WS_BHHN + h];
                float wr = ws[WS_W64 + h], wz = ws[WS_W64 + 128 + h], wn = ws[WS_W64 + 256 + h];
#pragma unroll
                for (int mt = 0; mt < 2; mt++) {
                    f32x4 R = mt ? aR1 : aR0;
                    f32x4 Z = mt ? aZ1 : aZ0;
                    f32x4 I = mt ? aI1 : aI0;
                    f32x4 N = mt ? aN1 : aN0;
                    float fls = 0.f;
#pragma unroll
                    for (int j = 0; j < 4; j++) {
                        int row = r0 + mt * 16 + (kq << 2) + j;
                        float tv = ts_s[row];
                        float r  = sigm(R[j] + bsr + tv * wr);
                        float z  = sigm(Z[j] + bsz + tv * wz);
                        float hn = N[j] + bhn;
                        float nn = tanh_fast(I[j] + bin + tv * wn + r * hn);
                        float hold = b2f(*(const unsigned short*)(hsb + row * 256 +
                                         ((h * 2) ^ ((row & 7) << 4))));
                        float nh = (1.f - z) * nn + z * hold;
                        nbase[(size_t)row * HID + h] = nh;
                        fls += nh;
                    }
                    fls += __shfl_xor(fls, 16);
                    fls += __shfl_xor(fls, 32);
                    if (lane < 16) atomicAdd(&fp[h], fls);
                }
            }
        }
        __syncthreads();
        if (t < 128) ws[WS_FPART + ((size_t)(b * 256 + chunk)) * 128 + t] = fp[t];
    }
    // ---- co writeout ----
#pragma unroll
    for (int p = 0; p < 2; p++) {
        int flat = (p * 512 + t) * 4;
        int c = flat >> 6, d = flat & 63;
        *(float4*)(ws + WS_CO + (size_t)(n0 + c) * 64 + d) = *(const float4*)(&co_s[c][d]);
    }
}

// ---------------- faction means ----------------
__global__ __launch_bounds__(128) void k2_fmean(float* __restrict__ ws)
{
    int bf = blockIdx.x;               // 64 = 8 branches * 8 factions
    int b = bf >> 3, f = bf & 7;
    int h = threadIdx.x;
    float s = 0.f;
    for (int j = 0; j < 32; j++)
        s += ws[WS_FPART + ((size_t)(b * 256 + f * 32 + j)) * 128 + h];
    ws[WS_FMEAN + (b * 8 + f) * 128 + h] = s * (1.f / 2048.f);
}

__global__ __launch_bounds__(1024) void k2_glob(float* __restrict__ ws)
{
    int t = threadIdx.x;
    int b = t >> 7, h = t & 127;
    float s = 0.f;
    for (int f = 0; f < 8; f++) s += ws[WS_FMEAN + (b * 8 + f) * 128 + h];
    ws[WS_GLOB + t] = s * 0.125f;
}

// ---------------- interference from chunk-sum statistics (no extra newh pass)
__global__ __launch_bounds__(128) void k4i(
    const float* __restrict__ mixW, const float* __restrict__ mixb,
    const int* __restrict__ step, float* __restrict__ ws)
{
    __shared__ float hm[1024];
    int t = threadIdx.x;
    bool deb = (step[0] > 5);
    for (int j = t; j < 1024; j += 128) {
        int b = j >> 7, hh = j & 127;
        float tot = 0.f, extra = 0.f;
        for (int f = 0; f < 8; f++) {
            float Sf = 0.f;
            for (int c = 0; c < 32; c++) {
                float v = ws[WS_FPART + ((size_t)(b * 256 + f * 32 + c)) * 128 + hh];
                tot += v;
                if (c < 8) Sf += v;
            }
            extra += 512.f * ws[WS_GLOB + b * 128 + hh]
                   - (0.85f * Sf + 76.8f * ws[WS_FMEAN + (b * 8 + f) * 128 + hh]);
        }
        // sync preserves per-branch mean; debate shifts it by 0.15*(glob - dmean(v'))
        hm[j] = (deb ? (tot + 0.15f * extra) : tot) * (1.f / 16384.f);
    }
    __syncthreads();
    float acc = mixb[t];
    for (int j = 0; j < 1024; j++) acc += hm[j] * mixW[t * 1024 + j];
    ws[WS_INTERF + t] = acc;
}

// ---------------- fused sync/debate blend + interf apply ----------------
__global__ __launch_bounds__(256) void k35_blend(
    float* __restrict__ newh, const float* __restrict__ ws,
    const int* __restrict__ step)
{
    int blk = blockIdx.x;              // 2048 = 8 * 256
    int b = blk >> 8, ck = blk & 255;
    int t = threadIdx.x;
    int h = t & 127, half = t >> 7;
    int base = ck * 64 + half * 32;
    int f = ck >> 5;
    bool deb = (step[0] > 5) && (((ck * 64) & 2047) < 512);
    float fm  = ws[WS_FMEAN + (b * 8 + f) * 128 + h];
    float gl  = ws[WS_GLOB + b * 128 + h];
    float itf = (b == 0) ? 0.05f * ws[WS_INTERF + h] : 0.f;
    for (int i = 0; i < 32; i++) {
        size_t idx = ((size_t)b * NCC + base + i) * HID + h;
        float v = newh[idx];
        v = 0.85f * v + 0.15f * fm;
        if (deb) v = 0.85f * v + 0.15f * gl;
        newh[idx] = v + itf;
    }
}

// ---------------- avg_t stats (max, denom, mean) ----------------
__global__ __launch_bounds__(1024) void kstat(float* __restrict__ ws, float* __restrict__ d_out)
{
    __shared__ float red[1024];
    __shared__ float msh;
    int t = threadIdx.x;
    float mx = -3.4e38f, sm = 0.f;
    for (int n = t; n < NCC; n += 1024) {
        float s = 0.f;
#pragma unroll
        for (int b = 0; b < 8; b++) s += ws[WS_TS + (size_t)b * NCC + n];
        s *= 0.125f;
        ws[WS_AVGT + n] = s;
        mx = fmaxf(mx, s);
        sm += s;
    }
    red[t] = mx; __syncthreads();
    for (int st = 512; st > 0; st >>= 1) { if (t < st) red[t] = fmaxf(red[t], red[t + st]); __syncthreads(); }
    if (t == 0) msh = red[0];
    __syncthreads();
    float m = msh;
    red[t] = sm; __syncthreads();
    for (int st = 512; st > 0; st >>= 1) { if (t < st) red[t] += red[t + st]; __syncthreads(); }
    if (t == 0) d_out[64] = red[0] * (1.f / (float)NCC);
    __syncthreads();
    float se = 0.f;
    for (int n = t; n < NCC; n += 1024) se += __expf(ws[WS_AVGT + n] - m);
    red[t] = se; __syncthreads();
    for (int st = 512; st > 0; st >>= 1) { if (t < st) red[t] += red[t + st]; __syncthreads(); }
    if (t == 0) { ws[WS_STAT] = m; ws[WS_STAT + 1] = red[0]; }
}

// ---------------- softmax-weighted cell_out partial reduction ----------------
__global__ __launch_bounds__(256) void kred(float* __restrict__ ws)
{
    __shared__ float wexp[64];
    __shared__ float red[256];
    int blk = blockIdx.x, t = threadIdx.x;
    int n0 = blk * 64;
    float m = ws[WS_STAT];
    if (t < 64) wexp[t] = __expf(ws[WS_AVGT + n0 + t] - m);
    __syncthreads();
    int d = t & 63, q = t >> 6;
    float s = 0.f;
    for (int i = 0; i < 16; i++) {
        int c = q * 16 + i;
        s += wexp[c] * ws[WS_CO + (size_t)(n0 + c) * 64 + d];
    }
    red[t] = s; __syncthreads();
    if (t < 64)
        ws[WS_PART2 + blk * 64 + t] = red[t] + red[64 + t] + red[128 + t] + red[192 + t];
}

__global__ __launch_bounds__(64) void kpred(
    const float* __restrict__ headW, const float* __restrict__ headb,
    float* __restrict__ ws, float* __restrict__ d_out)
{
    __shared__ float comb[64];
    int t = threadIdx.x;
    float den = ws[WS_STAT + 1];
    float s = 0.f;
    for (int blk = 0; blk < 256; blk++) s += ws[WS_PART2 + blk * 64 + t];
    comb[t] = s / den;
    __syncthreads();
    float p = headb[t];
    for (int d = 0; d < 64; d++) p += comb[d] * headW[t * 64 + d];
    d_out[t] = p;
}

extern "C" void kernel_launch(void* const* d_in, const int* in_sizes, int n_in,
                              void* d_out, int out_size, void* d_ws, size_t ws_size,
                              hipStream_t stream)
{
    const float* x       = (const float*)d_in[0];
    const float* noise   = (const float*)d_in[1];
    const float* amps    = (const float*)d_in[2];
    const float* hiddens = (const float*)d_in[3];
    const float* eaW1    = (const float*)d_in[4];
    const float* eaB1    = (const float*)d_in[5];
    const float* eaW2    = (const float*)d_in[6];
    const float* eaB2    = (const float*)d_in[7];
    const float* egW1    = (const float*)d_in[8];
    const float* egB1    = (const float*)d_in[9];
    const float* egW2    = (const float*)d_in[10];
    const float* egB2    = (const float*)d_in[11];
    const float* gWih    = (const float*)d_in[12];
    const float* gWhh    = (const float*)d_in[13];
    const float* gbih    = (const float*)d_in[14];
    const float* gbhh    = (const float*)d_in[15];
    const float* headW   = (const float*)d_in[16];
    const float* headb   = (const float*)d_in[17];
    const float* mixW    = (const float*)d_in[18];
    const float* mixb    = (const float*)d_in[19];
    const int*   step    = (const int*)d_in[20];

    float* out  = (float*)d_out;
    float* newh = out + 65;   // [pred(64), avg_t_mean(1), newh(8*16384*128)]
    float* ws   = (float*)d_ws;

    k0s<<<1, 256, 0, stream>>>(x, noise, amps, eaW1, eaB1, egW1, egB1,
                               eaB2, egB2, gbih, gbhh, gWih, ws);
    kfrag<<<120, 1024, 0, stream>>>(eaW1, egW1, eaW2, egW2, gWih, gWhh, ws);
    k1_cells<<<256, 512, 0, stream>>>(hiddens, newh, ws);
    k2_fmean<<<64, 128, 0, stream>>>(ws);
    k2_glob<<<1, 1024, 0, stream>>>(ws);
    k4i<<<1, 128, 0, stream>>>(mixW, mixb, step, ws);
    k35_blend<<<2048, 256, 0, stream>>>(newh, ws, step);
    kstat<<<1, 1024, 0, stream>>>(ws, out);
    kred<<<256, 256, 0, stream>>>(ws);
    kpred<<<1, 64, 0, stream>>>(headW, headb, ws, out);
}

// Round 3
// 249.223 us; speedup vs baseline: 6.1930x; 2.8156x over previous
//
#include <hip/hip_runtime.h>
#include <math.h>

#define NB   8
#define NCC  16384
#define HID  128

typedef __attribute__((ext_vector_type(8))) short short8;
typedef __attribute__((ext_vector_type(4))) float f32x4;

#define MFMA(a,b,c) __builtin_amdgcn_mfma_f32_16x16x32_bf16(a,b,c,0,0,0)

// ---- ws float offsets ----
#define WS_AABS   0
#define WS_BASE1  8
#define WS_BOUT   2056
#define WS_BSUMR  2120
#define WS_BSUMZ  2248
#define WS_BIHN   2376
#define WS_BHHN   2504
#define WS_W64    2632
#define WS_STAT   3016
#define WS_INTERF 3024
#define WS_FRAG   3152        // 61440 floats = 122880 bf16 frags
#define WS_SD     64592       // 64*128  (per-(b,f) debate-slice sums)
#define WS_HM     72784       // 1024
#define WS_AVGT   195664      // 16384
#define WS_CO     212048      // 16384*64
#define WS_FPART  1260624     // 8*256*128
#define WS_FMEAN  1522768     // 64*128
#define WS_GLOB   1530960     // 8*128
#define WS_PART2  1531984     // 256*64

// frag sub-offsets in shorts
#define FO_W1  0
#define FO_W2  32768
#define FO_WIH 49152
#define FO_WHH 73728

__device__ __forceinline__ unsigned short f2b(float f) {
    unsigned int u = __float_as_uint(f);
    unsigned int r = (u + 0x7fffu + ((u >> 16) & 1u)) >> 16;
    return (unsigned short)r;
}
__device__ __forceinline__ float b2f(unsigned short us) {
    return __uint_as_float(((unsigned int)us) << 16);
}
__device__ __forceinline__ float sigm(float x) {
    return __builtin_amdgcn_rcpf(1.f + __expf(-x));
}
__device__ __forceinline__ float tanh_fast(float x) {
    return 1.f - 2.f * __builtin_amdgcn_rcpf(__expf(2.f * x) + 1.f);
}

// ---------------- small prep: biases, xb-folded base, scalars ----------------
__global__ __launch_bounds__(256) void k0s(
    const float* __restrict__ x, const float* __restrict__ noise,
    const float* __restrict__ amps,
    const float* __restrict__ eaW1, const float* __restrict__ eaB1,
    const float* __restrict__ egW1, const float* __restrict__ egB1,
    const float* __restrict__ eaB2, const float* __restrict__ egB2,
    const float* __restrict__ gbih, const float* __restrict__ gbhh,
    const float* __restrict__ gWih, float* __restrict__ ws)
{
    __shared__ float xb[8][64];
    int t = threadIdx.x;
    for (int i = t; i < 512; i += 256) {
        int b = i >> 6, k = i & 63;
        xb[b][k] = x[k] + noise[b * 64 + k] * (0.05f * (float)(b + 1));
    }
    if (t == 0) {
        float s = 0.f;
        for (int b = 0; b < 8; b++) s += fabsf(amps[b]);
        s += 1e-8f;
        for (int b = 0; b < 8; b++) ws[WS_AABS + b] = fabsf(amps[b]) / s;
    }
    __syncthreads();
    for (int i = t; i < 2048; i += 256) {
        int b = i >> 8, n = i & 255;
        const float* Wp; float s;
        if (n < 128) { Wp = eaW1 + n * 192; s = eaB1[n]; }
        else         { Wp = egW1 + (n - 128) * 192; s = egB1[n - 128]; }
        for (int k = 0; k < 64; k++) s += xb[b][k] * Wp[k];
        ws[WS_BASE1 + i] = s;
    }
    if (t < 64) ws[WS_BOUT + t] = eaB2[t] - egB2[t];
    if (t < 128) {
        ws[WS_BSUMR + t] = gbih[t] + gbhh[t];
        ws[WS_BSUMZ + t] = gbih[128 + t] + gbhh[128 + t];
        ws[WS_BIHN + t]  = gbih[256 + t];
        ws[WS_BHHN + t]  = gbhh[256 + t];
    }
    for (int i = t; i < 384; i += 256) ws[WS_W64 + i] = gWih[i * 65 + 64];
}

// ---------------- weight -> MFMA B-fragment pre-swizzle (bf16) ----------------
__global__ __launch_bounds__(1024) void kfrag(
    const float* __restrict__ eaW1, const float* __restrict__ egW1,
    const float* __restrict__ eaW2, const float* __restrict__ egW2,
    const float* __restrict__ gWih, const float* __restrict__ gWhh,
    float* __restrict__ ws)
{
    int i = blockIdx.x * 1024 + threadIdx.x;
    if (i >= 122880) return;
    short* wsh = (short*)(ws + WS_FRAG);
    float v;
    if (i < 32768) {                       // W1: K=128, N=256 (a|g), KT=4
        int rel = i;
        int j = rel & 7, l = (rel >> 3) & 63, tk = rel >> 9;
        int kt = tk & 3, nt = tk >> 2;
        int n = nt * 16 + (l & 15), k = kt * 32 + ((l >> 4) << 3) + j;
        v = (n < 128) ? eaW1[n * 192 + 64 + k] : egW1[(n - 128) * 192 + 64 + k];
    } else if (i < 49152) {                // W2: K=256 ([A1|G1]), N=64, KT=8
        int rel = i - 32768;
        int j = rel & 7, l = (rel >> 3) & 63, tk = rel >> 9;
        int kt = tk & 7, nt = tk >> 3;
        int d = nt * 16 + (l & 15), k = kt * 32 + ((l >> 4) << 3) + j;
        v = (k < 128) ? eaW2[d * 128 + k] : -egW2[d * 128 + (k - 128)];
    } else if (i < 73728) {                // WIH: K=64, N=384, KT=2
        int rel = i - 49152;
        int j = rel & 7, l = (rel >> 3) & 63, tk = rel >> 9;
        int kt = tk & 1, nt = tk >> 1;
        int r = nt * 16 + (l & 15), k = kt * 32 + ((l >> 4) << 3) + j;
        v = gWih[r * 65 + k];
    } else {                               // WHH: K=128, N=384, KT=4
        int rel = i - 73728;
        int j = rel & 7, l = (rel >> 3) & 63, tk = rel >> 9;
        int kt = tk & 3, nt = tk >> 2;
        int r = nt * 16 + (l & 15), k = kt * 32 + ((l >> 4) << 3) + j;
        v = gWhh[r * 128 + k];
    }
    wsh[i] = (short)f2b(v);
}

// ---------------- main MFMA kernel: 256 blocks x 512 thr (8 waves), 64 cells, loop 8 branches
__global__ __launch_bounds__(512) void k1_cells(
    const float* __restrict__ hiddens, float* __restrict__ newh,
    float* __restrict__ ws)
{
    __shared__ char  hsb[64 * 256];    // bf16 [64][128] xor-swizzled
    __shared__ char  agb[64 * 512];    // bf16 [64][256] (relu a | relu g)
    __shared__ char  otb[64 * 128];    // bf16 [64][64]  (out)
    __shared__ float outf[64][68];     // f32 out, padded
    __shared__ float co_s[64][64];
    __shared__ float ts_s[64];
    __shared__ float tsum_s[64];
    __shared__ float fp[128];

    const int t    = threadIdx.x;
    const int lane = t & 63;
    const int w    = t >> 6;
    const int rh   = w >> 2;
    const int nq   = w & 3;
    const int col  = lane & 15;
    const int kq   = lane >> 4;
    const int r0   = rh * 32;
    const int chunk = blockIdx.x;
    const int n0   = chunk * 64;

    const short* wsh  = (const short*)(ws + WS_FRAG);
    const short8* W1F  = (const short8*)(wsh + FO_W1);
    const short8* W2F  = (const short8*)(wsh + FO_W2);
    const short8* WIHF = (const short8*)(wsh + FO_WIH);
    const short8* WHHF = (const short8*)(wsh + FO_WHH);

    for (int i = t; i < 4096; i += 512) ((float*)co_s)[i] = 0.f;
    if (t < 64) tsum_s[t] = 0.f;

    for (int b = 0; b < NB; b++) {
        if (t < 128) fp[t] = 0.f;
        // ---- stage hiddens -> bf16 LDS (swizzled) ----
        const float* hsrc = hiddens + ((size_t)(b * NCC + n0)) * HID;
#pragma unroll
        for (int p = 0; p < 2; p++) {
            int flat = (p * 512 + t) * 8;
            int row = flat >> 7;
            int cb  = (flat & 127) * 2;
            float4 u = *(const float4*)(hsrc + flat);
            float4 v = *(const float4*)(hsrc + flat + 4);
            unsigned int p0 = (unsigned)f2b(u.x) | ((unsigned)f2b(u.y) << 16);
            unsigned int p1 = (unsigned)f2b(u.z) | ((unsigned)f2b(u.w) << 16);
            unsigned int p2 = (unsigned)f2b(v.x) | ((unsigned)f2b(v.y) << 16);
            unsigned int p3 = (unsigned)f2b(v.z) | ((unsigned)f2b(v.w) << 16);
            uint4 pk = make_uint4(p0, p1, p2, p3);
            *(uint4*)(hsb + row * 256 + (cb ^ ((row & 7) << 4))) = pk;
        }
        __syncthreads();

        // ---- L1: [relu(a)|relu(g)] = relu(H @ W1^T + base1), 64x256, K=128 ----
        {
            short8 aH[2][4];
#pragma unroll
            for (int mt = 0; mt < 2; mt++)
#pragma unroll
                for (int ks = 0; ks < 4; ks++) {
                    int row = r0 + mt * 16 + col;
                    aH[mt][ks] = *(const short8*)(hsb + row * 256 +
                                   ((ks * 64 + (kq << 4)) ^ ((row & 7) << 4)));
                }
#pragma unroll
            for (int nti = 0; nti < 4; nti++) {
                int nt = nq * 4 + nti;
                f32x4 ac0 = {0.f, 0.f, 0.f, 0.f};
                f32x4 ac1 = {0.f, 0.f, 0.f, 0.f};
#pragma unroll
                for (int kt = 0; kt < 4; kt++) {
                    short8 bf = W1F[(nt * 4 + kt) * 64 + lane];
                    ac0 = MFMA(aH[0][kt], bf, ac0);
                    ac1 = MFMA(aH[1][kt], bf, ac1);
                }
                int n = nt * 16 + col;
                float bs = ws[WS_BASE1 + b * 256 + n];
#pragma unroll
                for (int mt = 0; mt < 2; mt++) {
                    f32x4 a = mt ? ac1 : ac0;
#pragma unroll
                    for (int j = 0; j < 4; j++) {
                        int row = r0 + mt * 16 + (kq << 2) + j;
                        float v = fmaxf(a[j] + bs, 0.f);
                        *(unsigned short*)(agb + row * 512 +
                            ((n * 2) ^ ((row & 7) << 4))) = f2b(v);
                    }
                }
            }
        }
        __syncthreads();

        // ---- L2: out = [A1|G1] @ [W2A;-W2G] + bout, 64x64, K=256 ----
        {
            int nt = nq;
            f32x4 ac0 = {0.f, 0.f, 0.f, 0.f};
            f32x4 ac1 = {0.f, 0.f, 0.f, 0.f};
#pragma unroll
            for (int kt = 0; kt < 8; kt++) {
                int kb = kt * 64 + (kq << 4);
                int ra = r0 + col, rb = r0 + 16 + col;
                short8 a0 = *(const short8*)(agb + ra * 512 + (kb ^ ((ra & 7) << 4)));
                short8 a1 = *(const short8*)(agb + rb * 512 + (kb ^ ((rb & 7) << 4)));
                short8 bf = W2F[(nt * 8 + kt) * 64 + lane];
                ac0 = MFMA(a0, bf, ac0);
                ac1 = MFMA(a1, bf, ac1);
            }
            int d = nt * 16 + col;
            float bo = ws[WS_BOUT + d];
#pragma unroll
            for (int mt = 0; mt < 2; mt++) {
                f32x4 a = mt ? ac1 : ac0;
#pragma unroll
                for (int j = 0; j < 4; j++) {
                    int row = r0 + mt * 16 + (kq << 2) + j;
                    float v = a[j] + bo;
                    outf[row][d] = v;
                    *(unsigned short*)(otb + row * 128 +
                        ((d * 2) ^ ((row & 7) << 4))) = f2b(v);
                }
            }
        }
        __syncthreads();

        // ---- tension, avg_t accumulate, co accumulate ----
        {
            int c = t >> 3, q = t & 7;
            float s = 0.f;
#pragma unroll
            for (int i = 0; i < 8; i++) { float v = outf[c][q * 8 + i]; s += v * v; }
            s += __shfl_xor(s, 1);
            s += __shfl_xor(s, 2);
            s += __shfl_xor(s, 4);
            if (q == 0) {
                float sv = s * (1.f / 64.f);
                ts_s[c] = sv;
                tsum_s[c] += sv;
            }
            float aab = ws[WS_AABS + b];
#pragma unroll
            for (int i = 0; i < 8; i++) {
                int e = t + 512 * i;
                int cc = e >> 6, dd = e & 63;
                co_s[cc][dd] += aab * outf[cc][dd];
            }
        }
        __syncthreads();

        // ---- GRU: gi (K=64 from out) + gh (K=128 from h) ----
        {
            float* nbase = newh + ((size_t)(b * NCC + n0)) * HID;
#pragma unroll
            for (int hgi = 0; hgi < 2; hgi++) {
                int hg = nq * 2 + hgi;
                f32x4 aR0 = {0.f,0.f,0.f,0.f}, aR1 = {0.f,0.f,0.f,0.f};
                f32x4 aZ0 = {0.f,0.f,0.f,0.f}, aZ1 = {0.f,0.f,0.f,0.f};
                f32x4 aI0 = {0.f,0.f,0.f,0.f}, aI1 = {0.f,0.f,0.f,0.f};
                f32x4 aN0 = {0.f,0.f,0.f,0.f}, aN1 = {0.f,0.f,0.f,0.f};
#pragma unroll
                for (int ks = 0; ks < 2; ks++) {
                    int kb = ks * 64 + (kq << 4);
                    int ra = r0 + col, rb = r0 + 16 + col;
                    short8 a0 = *(const short8*)(otb + ra * 128 + (kb ^ ((ra & 7) << 4)));
                    short8 a1 = *(const short8*)(otb + rb * 128 + (kb ^ ((rb & 7) << 4)));
                    short8 br = WIHF[(hg * 2 + ks) * 64 + lane];
                    short8 bz = WIHF[((hg + 8) * 2 + ks) * 64 + lane];
                    short8 bi = WIHF[((hg + 16) * 2 + ks) * 64 + lane];
                    aR0 = MFMA(a0, br, aR0); aR1 = MFMA(a1, br, aR1);
                    aZ0 = MFMA(a0, bz, aZ0); aZ1 = MFMA(a1, bz, aZ1);
                    aI0 = MFMA(a0, bi, aI0); aI1 = MFMA(a1, bi, aI1);
                }
#pragma unroll
                for (int ks = 0; ks < 4; ks++) {
                    int kb = ks * 64 + (kq << 4);
                    int ra = r0 + col, rb = r0 + 16 + col;
                    short8 a0 = *(const short8*)(hsb + ra * 256 + (kb ^ ((ra & 7) << 4)));
                    short8 a1 = *(const short8*)(hsb + rb * 256 + (kb ^ ((rb & 7) << 4)));
                    short8 br = WHHF[(hg * 4 + ks) * 64 + lane];
                    short8 bz = WHHF[((hg + 8) * 4 + ks) * 64 + lane];
                    short8 bn = WHHF[((hg + 16) * 4 + ks) * 64 + lane];
                    aR0 = MFMA(a0, br, aR0); aR1 = MFMA(a1, br, aR1);
                    aZ0 = MFMA(a0, bz, aZ0); aZ1 = MFMA(a1, bz, aZ1);
                    aN0 = MFMA(a0, bn, aN0); aN1 = MFMA(a1, bn, aN1);
                }
                int h = hg * 16 + col;
                float bsr = ws[WS_BSUMR + h], bsz = ws[WS_BSUMZ + h];
                float bin = ws[WS_BIHN + h], bhn = ws[WS_BHHN + h];
                float wr = ws[WS_W64 + h], wz = ws[WS_W64 + 128 + h], wn = ws[WS_W64 + 256 + h];
#pragma unroll
                for (int mt = 0; mt < 2; mt++) {
                    f32x4 R = mt ? aR1 : aR0;
                    f32x4 Z = mt ? aZ1 : aZ0;
                    f32x4 I = mt ? aI1 : aI0;
                    f32x4 N = mt ? aN1 : aN0;
                    float fls = 0.f;
#pragma unroll
                    for (int j = 0; j < 4; j++) {
                        int row = r0 + mt * 16 + (kq << 2) + j;
                        float tv = ts_s[row];
                        float r  = sigm(R[j] + bsr + tv * wr);
                        float z  = sigm(Z[j] + bsz + tv * wz);
                        float hn = N[j] + bhn;
                        float nn = tanh_fast(I[j] + bin + tv * wn + r * hn);
                        float hold = b2f(*(const unsigned short*)(hsb + row * 256 +
                                         ((h * 2) ^ ((row & 7) << 4))));
                        float nh = (1.f - z) * nn + z * hold;
                        nbase[(size_t)row * HID + h] = nh;
                        fls += nh;
                    }
                    fls += __shfl_xor(fls, 16);
                    fls += __shfl_xor(fls, 32);
                    if (lane < 16) atomicAdd(&fp[h], fls);
                }
            }
        }
        __syncthreads();
        if (t < 128) ws[WS_FPART + ((size_t)(b * 256 + chunk)) * 128 + t] = fp[t];
    }
    // ---- co + avg_t writeout ----
#pragma unroll
    for (int p = 0; p < 2; p++) {
        int flat = (p * 512 + t) * 4;
        int c = flat >> 6, d = flat & 63;
        *(float4*)(ws + WS_CO + (size_t)(n0 + c) * 64 + d) = *(const float4*)(&co_s[c][d]);
    }
    if (t < 64) ws[WS_AVGT + n0 + t] = tsum_s[t] * 0.125f;
}

// ---------------- faction means + debate-slice sums ----------------
__global__ __launch_bounds__(128) void k2_fmean(float* __restrict__ ws)
{
    int bf = blockIdx.x;               // 64 = 8 branches * 8 factions
    int b = bf >> 3, f = bf & 7;
    int h = threadIdx.x;
    float s = 0.f, s8 = 0.f;
    for (int j = 0; j < 32; j++) {
        float v = ws[WS_FPART + ((size_t)(b * 256 + f * 32 + j)) * 128 + h];
        s += v;
        if (j < 8) s8 += v;
    }
    ws[WS_FMEAN + (b * 8 + f) * 128 + h] = s * (1.f / 2048.f);
    ws[WS_SD + (b * 8 + f) * 128 + h] = s8;
}

__global__ __launch_bounds__(1024) void k2_glob(float* __restrict__ ws)
{
    int t = threadIdx.x;
    int b = t >> 7, h = t & 127;
    float s = 0.f;
    for (int f = 0; f < 8; f++) s += ws[WS_FMEAN + (b * 8 + f) * 128 + h];
    ws[WS_GLOB + t] = s * 0.125f;
}

// ---------------- hm vector (post-blend branch means), tiny ----------------
__global__ __launch_bounds__(1024) void k4hm(
    const int* __restrict__ step, float* __restrict__ ws)
{
    int t = threadIdx.x;
    int b = t >> 7, h = t & 127;
    float gl = ws[WS_GLOB + b * 128 + h];
    float tot = 16384.f * gl;
    if (step[0] > 5) {
        float sd = 0.f;
        for (int f = 0; f < 8; f++) sd += ws[WS_SD + (b * 8 + f) * 128 + h];
        float extra = 3481.6f * gl - 0.85f * sd;
        tot += 0.15f * extra;
    }
    ws[WS_HM + t] = tot * (1.f / 16384.f);
}

// ---------------- interference matvec: 128 blocks, one output each ----------
__global__ __launch_bounds__(256) void k4mv(
    const float* __restrict__ mixW, const float* __restrict__ mixb,
    float* __restrict__ ws)
{
    __shared__ float red[256];
    int h = blockIdx.x, t = threadIdx.x;
    float4 wv = *(const float4*)(mixW + (size_t)h * 1024 + t * 4);
    float4 hv = *(const float4*)(ws + WS_HM + t * 4);
    float s = wv.x * hv.x + wv.y * hv.y + wv.z * hv.z + wv.w * hv.w;
    red[t] = s; __syncthreads();
    for (int st = 128; st > 0; st >>= 1) { if (t < st) red[t] += red[t + st]; __syncthreads(); }
    if (t == 0) ws[WS_INTERF + h] = mixb[h] + red[0];
}

// ---------------- fused sync/debate blend + interf apply ----------------
__global__ __launch_bounds__(256) void k35_blend(
    float* __restrict__ newh, const float* __restrict__ ws,
    const int* __restrict__ step)
{
    int blk = blockIdx.x;              // 2048 = 8 * 256
    int b = blk >> 8, ck = blk & 255;
    int t = threadIdx.x;
    int h = t & 127, half = t >> 7;
    int base = ck * 64 + half * 32;
    int f = ck >> 5;
    bool deb = (step[0] > 5) && (((ck * 64) & 2047) < 512);
    float fm  = ws[WS_FMEAN + (b * 8 + f) * 128 + h];
    float gl  = ws[WS_GLOB + b * 128 + h];
    float itf = (b == 0) ? 0.05f * ws[WS_INTERF + h] : 0.f;
    for (int i = 0; i < 32; i++) {
        size_t idx = ((size_t)b * NCC + base + i) * HID + h;
        float v = newh[idx];
        v = 0.85f * v + 0.15f * fm;
        if (deb) v = 0.85f * v + 0.15f * gl;
        newh[idx] = v + itf;
    }
}

// ---------------- avg_t stats (max, denom, mean) ----------------
__global__ __launch_bounds__(1024) void kstat(float* __restrict__ ws, float* __restrict__ d_out)
{
    __shared__ float red[1024];
    __shared__ float msh;
    int t = threadIdx.x;
    float mx = -3.4e38f, sm = 0.f;
    for (int n = t; n < NCC; n += 1024) {
        float v = ws[WS_AVGT + n];
        mx = fmaxf(mx, v);
        sm += v;
    }
    red[t] = mx; __syncthreads();
    for (int st = 512; st > 0; st >>= 1) { if (t < st) red[t] = fmaxf(red[t], red[t + st]); __syncthreads(); }
    if (t == 0) msh = red[0];
    __syncthreads();
    float m = msh;
    red[t] = sm; __syncthreads();
    for (int st = 512; st > 0; st >>= 1) { if (t < st) red[t] += red[t + st]; __syncthreads(); }
    if (t == 0) d_out[64] = red[0] * (1.f / (float)NCC);
    __syncthreads();
    float se = 0.f;
    for (int n = t; n < NCC; n += 1024) se += __expf(ws[WS_AVGT + n] - m);
    red[t] = se; __syncthreads();
    for (int st = 512; st > 0; st >>= 1) { if (t < st) red[t] += red[t + st]; __syncthreads(); }
    if (t == 0) { ws[WS_STAT] = m; ws[WS_STAT + 1] = red[0]; }
}

// ---------------- softmax-weighted cell_out partial reduction ----------------
__global__ __launch_bounds__(256) void kred(float* __restrict__ ws)
{
    __shared__ float wexp[64];
    __shared__ float red[256];
    int blk = blockIdx.x, t = threadIdx.x;
    int n0 = blk * 64;
    float m = ws[WS_STAT];
    if (t < 64) wexp[t] = __expf(ws[WS_AVGT + n0 + t] - m);
    __syncthreads();
    int d = t & 63, q = t >> 6;
    float s = 0.f;
    for (int i = 0; i < 16; i++) {
        int c = q * 16 + i;
        s += wexp[c] * ws[WS_CO + (size_t)(n0 + c) * 64 + d];
    }
    red[t] = s; __syncthreads();
    if (t < 64)
        ws[WS_PART2 + blk * 64 + t] = red[t] + red[64 + t] + red[128 + t] + red[192 + t];
}

__global__ __launch_bounds__(256) void kpred(
    const float* __restrict__ headW, const float* __restrict__ headb,
    float* __restrict__ ws, float* __restrict__ d_out)
{
    __shared__ float red[256];
    __shared__ float comb[64];
    int t = threadIdx.x;
    int d = t & 63, q = t >> 6;
    float s = 0.f;
    for (int i = 0; i < 64; i++) s += ws[WS_PART2 + (q * 64 + i) * 64 + d];
    red[t] = s; __syncthreads();
    if (t < 64) comb[t] = (red[t] + red[64 + t] + red[128 + t] + red[192 + t]) / ws[WS_STAT + 1];
    __syncthreads();
    if (t < 64) {
        float p = headb[t];
        for (int d2 = 0; d2 < 64; d2++) p += comb[d2] * headW[t * 64 + d2];
        d_out[t] = p;
    }
}

extern "C" void kernel_launch(void* const* d_in, const int* in_sizes, int n_in,
                              void* d_out, int out_size, void* d_ws, size_t ws_size,
                              hipStream_t stream)
{
    const float* x       = (const float*)d_in[0];
    const float* noise   = (const float*)d_in[1];
    const float* amps    = (const float*)d_in[2];
    const float* hiddens = (const float*)d_in[3];
    const float* eaW1    = (const float*)d_in[4];
    const float* eaB1    = (const float*)d_in[5];
    const float* eaW2    = (const float*)d_in[6];
    const float* eaB2    = (const float*)d_in[7];
    const float* egW1    = (const float*)d_in[8];
    const float* egB1    = (const float*)d_in[9];
    const float* egW2    = (const float*)d_in[10];
    const float* egB2    = (const float*)d_in[11];
    const float* gWih    = (const float*)d_in[12];
    const float* gWhh    = (const float*)d_in[13];
    const float* gbih    = (const float*)d_in[14];
    const float* gbhh    = (const float*)d_in[15];
    const float* headW   = (const float*)d_in[16];
    const float* headb   = (const float*)d_in[17];
    const float* mixW    = (const float*)d_in[18];
    const float* mixb    = (const float*)d_in[19];
    const int*   step    = (const int*)d_in[20];

    float* out  = (float*)d_out;
    float* newh = out + 65;   // [pred(64), avg_t_mean(1), newh(8*16384*128)]
    float* ws   = (float*)d_ws;

    k0s<<<1, 256, 0, stream>>>(x, noise, amps, eaW1, eaB1, egW1, egB1,
                               eaB2, egB2, gbih, gbhh, gWih, ws);
    kfrag<<<120, 1024, 0, stream>>>(eaW1, egW1, eaW2, egW2, gWih, gWhh, ws);
    k1_cells<<<256, 512, 0, stream>>>(hiddens, newh, ws);
    k2_fmean<<<64, 128, 0, stream>>>(ws);
    k2_glob<<<1, 1024, 0, stream>>>(ws);
    k4hm<<<1, 1024, 0, stream>>>(step, ws);
    k4mv<<<128, 256, 0, stream>>>(mixW, mixb, ws);
    k35_blend<<<2048, 256, 0, stream>>>(newh, ws, step);
    kstat<<<1, 1024, 0, stream>>>(ws, out);
    kred<<<256, 256, 0, stream>>>(ws);
    kpred<<<1, 256, 0, stream>>>(headW, headb, ws, out);
}

// Round 5
// 232.344 us; speedup vs baseline: 6.6430x; 1.0727x over previous
//
#include <hip/hip_runtime.h>
#include <math.h>

#define NB   8
#define NCC  16384
#define HID  128

typedef __attribute__((ext_vector_type(8))) short short8;
typedef __attribute__((ext_vector_type(4))) float f32x4;

#define MFMA(a,b,c) __builtin_amdgcn_mfma_f32_16x16x32_bf16(a,b,c,0,0,0)

// ---- ws float offsets ----
#define WS_AABS   0
#define WS_BASE1  8
#define WS_BOUT   2056
#define WS_BSUMR  2120
#define WS_BSUMZ  2248
#define WS_BIHN   2376
#define WS_BHHN   2504
#define WS_W64    2632
#define WS_STAT   3016
#define WS_INTERF 3024
#define WS_FRAG   3152        // 61440 floats = 122880 bf16 frags
#define WS_SD     64592       // 64*128
#define WS_HM     72784       // 1024
#define WS_AVGT   195664      // 16384   (zeroed each call, atomic-accumulated)
#define WS_CO     212048      // 16384*64 (zeroed each call, atomic-accumulated)
#define WS_FPART  1260624     // 8*256*128 (zeroed each call, atomic-accumulated)
#define WS_FMEAN  1522768     // 64*128
#define WS_GLOB   1530960     // 8*128
#define WS_PART2  1531984     // 256*64
#define WS_ZLEN   1327104     // floats from WS_AVGT through end of FPART

// frag sub-offsets in shorts
#define FO_W1  0
#define FO_W2  32768
#define FO_WIH 49152
#define FO_WHH 73728

__device__ __forceinline__ unsigned short f2b(float f) {
    unsigned int u = __float_as_uint(f);
    unsigned int r = (u + 0x7fffu + ((u >> 16) & 1u)) >> 16;
    return (unsigned short)r;
}
__device__ __forceinline__ float b2f(unsigned short us) {
    return __uint_as_float(((unsigned int)us) << 16);
}
__device__ __forceinline__ float sigm(float x) {
    return __builtin_amdgcn_rcpf(1.f + __expf(-x));
}
__device__ __forceinline__ float tanh_fast(float x) {
    return 1.f - 2.f * __builtin_amdgcn_rcpf(__expf(2.f * x) + 1.f);
}
__device__ __forceinline__ void stg(char* dst, int row, int cb, float4 u, float4 v) {
    unsigned int p0 = (unsigned)f2b(u.x) | ((unsigned)f2b(u.y) << 16);
    unsigned int p1 = (unsigned)f2b(u.z) | ((unsigned)f2b(u.w) << 16);
    unsigned int p2 = (unsigned)f2b(v.x) | ((unsigned)f2b(v.y) << 16);
    unsigned int p3 = (unsigned)f2b(v.z) | ((unsigned)f2b(v.w) << 16);
    uint4 pk = make_uint4(p0, p1, p2, p3);
    *(uint4*)(dst + row * 256 + (cb ^ ((row & 7) << 4))) = pk;
}

// ---------------- small prep: biases, xb-folded base, scalars ----------------
__global__ __launch_bounds__(256) void k0s(
    const float* __restrict__ x, const float* __restrict__ noise,
    const float* __restrict__ amps,
    const float* __restrict__ eaW1, const float* __restrict__ eaB1,
    const float* __restrict__ egW1, const float* __restrict__ egB1,
    const float* __restrict__ eaB2, const float* __restrict__ egB2,
    const float* __restrict__ gbih, const float* __restrict__ gbhh,
    const float* __restrict__ gWih, float* __restrict__ ws)
{
    __shared__ float xb[8][64];
    int t = threadIdx.x;
    for (int i = t; i < 512; i += 256) {
        int b = i >> 6, k = i & 63;
        xb[b][k] = x[k] + noise[b * 64 + k] * (0.05f * (float)(b + 1));
    }
    if (t == 0) {
        float s = 0.f;
        for (int b = 0; b < 8; b++) s += fabsf(amps[b]);
        s += 1e-8f;
        for (int b = 0; b < 8; b++) ws[WS_AABS + b] = fabsf(amps[b]) / s;
    }
    __syncthreads();
    for (int i = t; i < 2048; i += 256) {
        int b = i >> 8, n = i & 255;
        const float* Wp; float s;
        if (n < 128) { Wp = eaW1 + n * 192; s = eaB1[n]; }
        else         { Wp = egW1 + (n - 128) * 192; s = egB1[n - 128]; }
        for (int k = 0; k < 64; k++) s += xb[b][k] * Wp[k];
        ws[WS_BASE1 + i] = s;
    }
    if (t < 64) ws[WS_BOUT + t] = eaB2[t] - egB2[t];
    if (t < 128) {
        ws[WS_BSUMR + t] = gbih[t] + gbhh[t];
        ws[WS_BSUMZ + t] = gbih[128 + t] + gbhh[128 + t];
        ws[WS_BIHN + t]  = gbih[256 + t];
        ws[WS_BHHN + t]  = gbhh[256 + t];
    }
    for (int i = t; i < 384; i += 256) ws[WS_W64 + i] = gWih[i * 65 + 64];
}

// ---------------- weight -> MFMA B-fragment pre-swizzle + accumulator zeroing
__global__ __launch_bounds__(1024) void kfrag(
    const float* __restrict__ eaW1, const float* __restrict__ egW1,
    const float* __restrict__ eaW2, const float* __restrict__ egW2,
    const float* __restrict__ gWih, const float* __restrict__ gWhh,
    float* __restrict__ ws)
{
    int i = blockIdx.x * 1024 + threadIdx.x;
    for (int z = i; z < WS_ZLEN; z += 122880)
        ws[WS_AVGT + z] = 0.f;
    if (i >= 122880) return;
    short* wsh = (short*)(ws + WS_FRAG);
    float v;
    if (i < 32768) {                       // W1: K=128, N=256 (a|g), KT=4
        int rel = i;
        int j = rel & 7, l = (rel >> 3) & 63, tk = rel >> 9;
        int kt = tk & 3, nt = tk >> 2;
        int n = nt * 16 + (l & 15), k = kt * 32 + ((l >> 4) << 3) + j;
        v = (n < 128) ? eaW1[n * 192 + 64 + k] : egW1[(n - 128) * 192 + 64 + k];
    } else if (i < 49152) {                // W2: K=256 ([A1|G1]), N=64, KT=8
        int rel = i - 32768;
        int j = rel & 7, l = (rel >> 3) & 63, tk = rel >> 9;
        int kt = tk & 7, nt = tk >> 3;
        int d = nt * 16 + (l & 15), k = kt * 32 + ((l >> 4) << 3) + j;
        v = (k < 128) ? eaW2[d * 128 + k] : -egW2[d * 128 + (k - 128)];
    } else if (i < 73728) {                // WIH: K=64, N=384, KT=2
        int rel = i - 49152;
        int j = rel & 7, l = (rel >> 3) & 63, tk = rel >> 9;
        int kt = tk & 1, nt = tk >> 1;
        int r = nt * 16 + (l & 15), k = kt * 32 + ((l >> 4) << 3) + j;
        v = gWih[r * 65 + k];
    } else {                               // WHH: K=128, N=384, KT=4
        int rel = i - 73728;
        int j = rel & 7, l = (rel >> 3) & 63, tk = rel >> 9;
        int kt = tk & 3, nt = tk >> 2;
        int r = nt * 16 + (l & 15), k = kt * 32 + ((l >> 4) << 3) + j;
        v = gWhh[r * 128 + k];
    }
    wsh[i] = (short)f2b(v);
}

// ---------------- main MFMA kernel ----------------
// grid 1024 = 256 chunks (64 cells) x 4 branch-groups (2 branches each)
// 512 threads = 8 waves; LDS ~73KB -> 2 blocks/CU; VGPR capped 128 -> 16 waves/CU
__global__ __launch_bounds__(512, 4) void k1_cells(
    const float* __restrict__ hiddens, float* __restrict__ newh,
    float* __restrict__ ws)
{
    __shared__ char  hsb[2][64 * 256];  // bf16 [64][128] xor-swizzled, double buffer
    __shared__ char  agb[64 * 512];     // bf16 [64][256] (relu a | relu g)
    __shared__ char  otb[64 * 128];     // bf16 [64][64]  (out)
    __shared__ float ts_s[64];
    __shared__ float tsum_s[64];

    const int t    = threadIdx.x;
    const int lane = t & 63;
    const int w    = t >> 6;
    const int rh   = w >> 2;
    const int nq   = w & 3;
    const int col  = lane & 15;
    const int kq   = lane >> 4;
    const int r0   = rh * 32;
    const int chunk = blockIdx.x & 255;
    const int bg    = blockIdx.x >> 8;
    const int n0   = chunk * 64;
    const int b0   = bg * 2;

    const short* wsh   = (const short*)(ws + WS_FRAG);
    const short8* W1F  = (const short8*)(wsh + FO_W1);
    const short8* W2F  = (const short8*)(wsh + FO_W2);
    const short8* WIHF = (const short8*)(wsh + FO_WIH);
    const short8* WHHF = (const short8*)(wsh + FO_WHH);

    float co_reg[8];
#pragma unroll
    for (int i = 0; i < 8; i++) co_reg[i] = 0.f;
    if (t < 64) tsum_s[t] = 0.f;

    const int flat0 = t * 8;
    const int flat1 = (512 + t) * 8;
    const int srow0 = flat0 >> 7, scb0 = (flat0 & 127) * 2;
    const int srow1 = flat1 >> 7, scb1 = (flat1 & 127) * 2;

    // prologue: stage branch b0, issue prefetch for b0+1
    {
        const float* hs = hiddens + ((size_t)(b0 * NCC + n0)) * HID;
        float4 a0 = *(const float4*)(hs + flat0);
        float4 a1 = *(const float4*)(hs + flat0 + 4);
        float4 c0 = *(const float4*)(hs + flat1);
        float4 c1 = *(const float4*)(hs + flat1 + 4);
        stg(hsb[0], srow0, scb0, a0, a1);
        stg(hsb[0], srow1, scb1, c0, c1);
    }
    const float* hs1 = hiddens + ((size_t)((b0 + 1) * NCC + n0)) * HID;
    float4 pfa0 = *(const float4*)(hs1 + flat0);
    float4 pfa1 = *(const float4*)(hs1 + flat0 + 4);
    float4 pfb0 = *(const float4*)(hs1 + flat1);
    float4 pfb1 = *(const float4*)(hs1 + flat1 + 4);
    __syncthreads();

#pragma unroll
    for (int bi = 0; bi < 2; bi++) {
        const int b = b0 + bi;
        const char* hcur = hsb[bi];
        if (t < 64) ts_s[t] = 0.f;

        // ---- L1: [relu(a)|relu(g)] = relu(H @ W1^T + base1), 64x256, K=128 ----
        {
            short8 aH[2][4];
#pragma unroll
            for (int mt = 0; mt < 2; mt++)
#pragma unroll
                for (int ks = 0; ks < 4; ks++) {
                    int row = r0 + mt * 16 + col;
                    aH[mt][ks] = *(const short8*)(hcur + row * 256 +
                                   ((ks * 64 + (kq << 4)) ^ ((row & 7) << 4)));
                }
#pragma unroll
            for (int nti = 0; nti < 4; nti++) {
                int nt = nq * 4 + nti;
                f32x4 ac0 = {0.f, 0.f, 0.f, 0.f};
                f32x4 ac1 = {0.f, 0.f, 0.f, 0.f};
#pragma unroll
                for (int kt = 0; kt < 4; kt++) {
                    short8 bf = W1F[(nt * 4 + kt) * 64 + lane];
                    ac0 = MFMA(aH[0][kt], bf, ac0);
                    ac1 = MFMA(aH[1][kt], bf, ac1);
                }
                int n = nt * 16 + col;
                float bs = ws[WS_BASE1 + b * 256 + n];
#pragma unroll
                for (int mt = 0; mt < 2; mt++) {
                    f32x4 a = mt ? ac1 : ac0;
#pragma unroll
                    for (int j = 0; j < 4; j++) {
                        int row = r0 + mt * 16 + (kq << 2) + j;
                        float v = fmaxf(a[j] + bs, 0.f);
                        *(unsigned short*)(agb + row * 512 +
                            ((n * 2) ^ ((row & 7) << 4))) = f2b(v);
                    }
                }
            }
        }
        __syncthreads();  // A: agb ready

        // ---- L2: out = [A1|G1] @ [W2A;-W2G] + bout; tension + co in regs ----
        {
            f32x4 ac0 = {0.f, 0.f, 0.f, 0.f};
            f32x4 ac1 = {0.f, 0.f, 0.f, 0.f};
#pragma unroll
            for (int kt = 0; kt < 8; kt++) {
                int kb = kt * 64 + (kq << 4);
                int ra = r0 + col, rb = r0 + 16 + col;
                short8 a0 = *(const short8*)(agb + ra * 512 + (kb ^ ((ra & 7) << 4)));
                short8 a1 = *(const short8*)(agb + rb * 512 + (kb ^ ((rb & 7) << 4)));
                short8 bf = W2F[(nq * 8 + kt) * 64 + lane];
                ac0 = MFMA(a0, bf, ac0);
                ac1 = MFMA(a1, bf, ac1);
            }
            int d = nq * 16 + col;
            float bo = ws[WS_BOUT + d];
            float aab = ws[WS_AABS + b];
#pragma unroll
            for (int mt = 0; mt < 2; mt++) {
                f32x4 a = mt ? ac1 : ac0;
#pragma unroll
                for (int j = 0; j < 4; j++) {
                    int row = r0 + mt * 16 + (kq << 2) + j;
                    float v = a[j] + bo;
                    *(unsigned short*)(otb + row * 128 +
                        ((d * 2) ^ ((row & 7) << 4))) = f2b(v);
                    co_reg[mt * 4 + j] += aab * v;
                    float sq = v * v;
                    sq += __shfl_xor(sq, 1);
                    sq += __shfl_xor(sq, 2);
                    sq += __shfl_xor(sq, 4);
                    sq += __shfl_xor(sq, 8);
                    if (col == 0) atomicAdd(&ts_s[row], sq);
                }
            }
        }
        __syncthreads();  // B: otb + ts_s ready

        // ---- GRU + prefetch write ----
        if (bi == 0) {
            stg(hsb[1], srow0, scb0, pfa0, pfa1);
            stg(hsb[1], srow1, scb1, pfb0, pfb1);
        }
        if (t < 64) tsum_s[t] += ts_s[t];
        {
            float* nbase = newh + ((size_t)(b * NCC + n0)) * HID;
#pragma unroll
            for (int hgi = 0; hgi < 2; hgi++) {
                int hg = nq * 2 + hgi;
                f32x4 aR0 = {0.f,0.f,0.f,0.f}, aR1 = {0.f,0.f,0.f,0.f};
                f32x4 aZ0 = {0.f,0.f,0.f,0.f}, aZ1 = {0.f,0.f,0.f,0.f};
                f32x4 aI0 = {0.f,0.f,0.f,0.f}, aI1 = {0.f,0.f,0.f,0.f};
                f32x4 aN0 = {0.f,0.f,0.f,0.f}, aN1 = {0.f,0.f,0.f,0.f};
#pragma unroll
                for (int ks = 0; ks < 2; ks++) {
                    int kb = ks * 64 + (kq << 4);
                    int ra = r0 + col, rb = r0 + 16 + col;
                    short8 a0 = *(const short8*)(otb + ra * 128 + (kb ^ ((ra & 7) << 4)));
                    short8 a1 = *(const short8*)(otb + rb * 128 + (kb ^ ((rb & 7) << 4)));
                    short8 br = WIHF[(hg * 2 + ks) * 64 + lane];
                    short8 bz = WIHF[((hg + 8) * 2 + ks) * 64 + lane];
                    short8 bi_ = WIHF[((hg + 16) * 2 + ks) * 64 + lane];
                    aR0 = MFMA(a0, br, aR0); aR1 = MFMA(a1, br, aR1);
                    aZ0 = MFMA(a0, bz, aZ0); aZ1 = MFMA(a1, bz, aZ1);
                    aI0 = MFMA(a0, bi_, aI0); aI1 = MFMA(a1, bi_, aI1);
                }
#pragma unroll
                for (int ks = 0; ks < 4; ks++) {
                    int kb = ks * 64 + (kq << 4);
                    int ra = r0 + col, rb = r0 + 16 + col;
                    short8 a0 = *(const short8*)(hcur + ra * 256 + (kb ^ ((ra & 7) << 4)));
                    short8 a1 = *(const short8*)(hcur + rb * 256 + (kb ^ ((rb & 7) << 4)));
                    short8 br = WHHF[(hg * 4 + ks) * 64 + lane];
                    short8 bz = WHHF[((hg + 8) * 4 + ks) * 64 + lane];
                    short8 bn = WHHF[((hg + 16) * 4 + ks) * 64 + lane];
                    aR0 = MFMA(a0, br, aR0); aR1 = MFMA(a1, br, aR1);
                    aZ0 = MFMA(a0, bz, aZ0); aZ1 = MFMA(a1, bz, aZ1);
                    aN0 = MFMA(a0, bn, aN0); aN1 = MFMA(a1, bn, aN1);
                }
                int h = hg * 16 + col;
                float bsr = ws[WS_BSUMR + h], bsz = ws[WS_BSUMZ + h];
                float bin = ws[WS_BIHN + h], bhn = ws[WS_BHHN + h];
                float wr = ws[WS_W64 + h], wz = ws[WS_W64 + 128 + h], wn = ws[WS_W64 + 256 + h];
                float flsum = 0.f;
#pragma unroll
                for (int mt = 0; mt < 2; mt++) {
                    f32x4 R = mt ? aR1 : aR0;
                    f32x4 Z = mt ? aZ1 : aZ0;
                    f32x4 I = mt ? aI1 : aI0;
                    f32x4 N = mt ? aN1 : aN0;
#pragma unroll
                    for (int j = 0; j < 4; j++) {
                        int row = r0 + mt * 16 + (kq << 2) + j;
                        float tv = ts_s[row] * (1.f / 64.f);
                        float r  = sigm(R[j] + bsr + tv * wr);
                        float z  = sigm(Z[j] + bsz + tv * wz);
                        float hn = N[j] + bhn;
                        float nn = tanh_fast(I[j] + bin + tv * wn + r * hn);
                        float hold = b2f(*(const unsigned short*)(hcur + row * 256 +
                                         ((h * 2) ^ ((row & 7) << 4))));
                        float nh = (1.f - z) * nn + z * hold;
                        nbase[(size_t)row * HID + h] = nh;
                        flsum += nh;
                    }
                }
                flsum += __shfl_xor(flsum, 16);
                flsum += __shfl_xor(flsum, 32);
                if (kq == 0)
                    atomicAdd(ws + WS_FPART + ((size_t)(b * 256 + chunk)) * 128 + h, flsum);
            }
        }
        __syncthreads();  // C: hsb[next] ready; LDS free for next branch
    }

    // ---- epilogue: co + avg_t accumulate to global ----
    {
        int d = nq * 16 + col;
#pragma unroll
        for (int mt = 0; mt < 2; mt++)
#pragma unroll
            for (int j = 0; j < 4; j++) {
                int row = r0 + mt * 16 + (kq << 2) + j;
                atomicAdd(ws + WS_CO + (size_t)(n0 + row) * 64 + d, co_reg[mt * 4 + j]);
            }
    }
    // ts_s held raw sum(out^2) (no /64); avg_t = sum_b ts/(64*8) = tsum * (1/512)
    if (t < 64) atomicAdd(ws + WS_AVGT + n0 + t, tsum_s[t] * (1.f / 512.f));
}

// ---------------- faction means + debate-slice sums ----------------
__global__ __launch_bounds__(128) void k2_fmean(float* __restrict__ ws)
{
    int bf = blockIdx.x;               // 64 = 8 branches * 8 factions
    int b = bf >> 3, f = bf & 7;
    int h = threadIdx.x;
    float s = 0.f, s8 = 0.f;
    for (int j = 0; j < 32; j++) {
        float v = ws[WS_FPART + ((size_t)(b * 256 + f * 32 + j)) * 128 + h];
        s += v;
        if (j < 8) s8 += v;
    }
    ws[WS_FMEAN + (b * 8 + f) * 128 + h] = s * (1.f / 2048.f);
    ws[WS_SD + (b * 8 + f) * 128 + h] = s8;
}

__global__ __launch_bounds__(1024) void k2_glob(float* __restrict__ ws)
{
    int t = threadIdx.x;
    int b = t >> 7, h = t & 127;
    float s = 0.f;
    for (int f = 0; f < 8; f++) s += ws[WS_FMEAN + (b * 8 + f) * 128 + h];
    ws[WS_GLOB + t] = s * 0.125f;
}

// ---------------- hm vector (post-blend branch means) ----------------
__global__ __launch_bounds__(1024) void k4hm(
    const int* __restrict__ step, float* __restrict__ ws)
{
    int t = threadIdx.x;
    int b = t >> 7, h = t & 127;
    float gl = ws[WS_GLOB + b * 128 + h];
    float tot = 16384.f * gl;
    if (step[0] > 5) {
        float sd = 0.f;
        for (int f = 0; f < 8; f++) sd += ws[WS_SD + (b * 8 + f) * 128 + h];
        float extra = 3481.6f * gl - 0.85f * sd;
        tot += 0.15f * extra;
    }
    ws[WS_HM + t] = tot * (1.f / 16384.f);
}

// ---------------- interference matvec ----------------
__global__ __launch_bounds__(256) void k4mv(
    const float* __restrict__ mixW, const float* __restrict__ mixb,
    float* __restrict__ ws)
{
    __shared__ float red[256];
    int h = blockIdx.x, t = threadIdx.x;
    float4 wv = *(const float4*)(mixW + (size_t)h * 1024 + t * 4);
    float4 hv = *(const float4*)(ws + WS_HM + t * 4);
    float s = wv.x * hv.x + wv.y * hv.y + wv.z * hv.z + wv.w * hv.w;
    red[t] = s; __syncthreads();
    for (int st = 128; st > 0; st >>= 1) { if (t < st) red[t] += red[t + st]; __syncthreads(); }
    if (t == 0) ws[WS_INTERF + h] = mixb[h] + red[0];
}

// ---------------- fused sync/debate blend + interf apply ----------------
__global__ __launch_bounds__(256) void k35_blend(
    float* __restrict__ newh, const float* __restrict__ ws,
    const int* __restrict__ step)
{
    int blk = blockIdx.x;              // 2048 = 8 * 256
    int b = blk >> 8, ck = blk & 255;
    int t = threadIdx.x;
    int h = t & 127, half = t >> 7;
    int base = ck * 64 + half * 32;
    int f = ck >> 5;
    bool deb = (step[0] > 5) && (((ck * 64) & 2047) < 512);
    float fm  = ws[WS_FMEAN + (b * 8 + f) * 128 + h];
    float gl  = ws[WS_GLOB + b * 128 + h];
    float itf = (b == 0) ? 0.05f * ws[WS_INTERF + h] : 0.f;
    for (int i = 0; i < 32; i++) {
        size_t idx = ((size_t)b * NCC + base + i) * HID + h;
        float v = newh[idx];
        v = 0.85f * v + 0.15f * fm;
        if (deb) v = 0.85f * v + 0.15f * gl;
        newh[idx] = v + itf;
    }
}

// ---------------- avg_t stats (max, denom, mean) ----------------
__global__ __launch_bounds__(1024) void kstat(float* __restrict__ ws, float* __restrict__ d_out)
{
    __shared__ float red[1024];
    __shared__ float msh;
    int t = threadIdx.x;
    float mx = -3.4e38f, sm = 0.f;
    for (int n = t; n < NCC; n += 1024) {
        float v = ws[WS_AVGT + n];
        mx = fmaxf(mx, v);
        sm += v;
    }
    red[t] = mx; __syncthreads();
    for (int st = 512; st > 0; st >>= 1) { if (t < st) red[t] = fmaxf(red[t], red[t + st]); __syncthreads(); }
    if (t == 0) msh = red[0];
    __syncthreads();
    float m = msh;
    red[t] = sm; __syncthreads();
    for (int st = 512; st > 0; st >>= 1) { if (t < st) red[t] += red[t + st]; __syncthreads(); }
    if (t == 0) d_out[64] = red[0] * (1.f / (float)NCC);
    __syncthreads();
    float se = 0.f;
    for (int n = t; n < NCC; n += 1024) se += __expf(ws[WS_AVGT + n] - m);
    red[t] = se; __syncthreads();
    for (int st = 512; st > 0; st >>= 1) { if (t < st) red[t] += red[t + st]; __syncthreads(); }
    if (t == 0) { ws[WS_STAT] = m; ws[WS_STAT + 1] = red[0]; }
}

// ---------------- softmax-weighted cell_out partial reduction ----------------
__global__ __launch_bounds__(256) void kred(float* __restrict__ ws)
{
    __shared__ float wexp[64];
    __shared__ float red[256];
    int blk = blockIdx.x, t = threadIdx.x;
    int n0 = blk * 64;
    float m = ws[WS_STAT];
    if (t < 64) wexp[t] = __expf(ws[WS_AVGT + n0 + t] - m);
    __syncthreads();
    int d = t & 63, q = t >> 6;
    float s = 0.f;
    for (int i = 0; i < 16; i++) {
        int c = q * 16 + i;
        s += wexp[c] * ws[WS_CO + (size_t)(n0 + c) * 64 + d];
    }
    red[t] = s; __syncthreads();
    if (t < 64)
        ws[WS_PART2 + blk * 64 + t] = red[t] + red[64 + t] + red[128 + t] + red[192 + t];
}

__global__ __launch_bounds__(256) void kpred(
    const float* __restrict__ headW, const float* __restrict__ headb,
    float* __restrict__ ws, float* __restrict__ d_out)
{
    __shared__ float red[256];
    __shared__ float comb[64];
    int t = threadIdx.x;
    int d = t & 63, q = t >> 6;
    float s = 0.f;
    for (int i = 0; i < 64; i++) s += ws[WS_PART2 + (q * 64 + i) * 64 + d];
    red[t] = s; __syncthreads();
    if (t < 64) comb[t] = (red[t] + red[64 + t] + red[128 + t] + red[192 + t]) / ws[WS_STAT + 1];
    __syncthreads();
    if (t < 64) {
        float p = headb[t];
        for (int d2 = 0; d2 < 64; d2++) p += comb[d2] * headW[t * 64 + d2];
        d_out[t] = p;
    }
}

extern "C" void kernel_launch(void* const* d_in, const int* in_sizes, int n_in,
                              void* d_out, int out_size, void* d_ws, size_t ws_size,
                              hipStream_t stream)
{
    const float* x       = (const float*)d_in[0];
    const float* noise   = (const float*)d_in[1];
    const float* amps    = (const float*)d_in[2];
    const float* hiddens = (const float*)d_in[3];
    const float* eaW1    = (const float*)d_in[4];
    const float* eaB1    = (const float*)d_in[5];
    const float* eaW2    = (const float*)d_in[6];
    const float* eaB2    = (const float*)d_in[7];
    const float* egW1    = (const float*)d_in[8];
    const float* egB1    = (const float*)d_in[9];
    const float* egW2    = (const float*)d_in[10];
    const float* egB2    = (const float*)d_in[11];
    const float* gWih    = (const float*)d_in[12];
    const float* gWhh    = (const float*)d_in[13];
    const float* gbih    = (const float*)d_in[14];
    const float* gbhh    = (const float*)d_in[15];
    const float* headW   = (const float*)d_in[16];
    const float* headb   = (const float*)d_in[17];
    const float* mixW    = (const float*)d_in[18];
    const float* mixb    = (const float*)d_in[19];
    const int*   step    = (const int*)d_in[20];

    float* out  = (float*)d_out;
    float* newh = out + 65;   // [pred(64), avg_t_mean(1), newh(8*16384*128)]
    float* ws   = (float*)d_ws;

    k0s<<<1, 256, 0, stream>>>(x, noise, amps, eaW1, eaB1, egW1, egB1,
                               eaB2, egB2, gbih, gbhh, gWih, ws);
    kfrag<<<120, 1024, 0, stream>>>(eaW1, egW1, eaW2, egW2, gWih, gWhh, ws);
    k1_cells<<<1024, 512, 0, stream>>>(hiddens, newh, ws);
    k2_fmean<<<64, 128, 0, stream>>>(ws);
    k2_glob<<<1, 1024, 0, stream>>>(ws);
    k4hm<<<1, 1024, 0, stream>>>(step, ws);
    k4mv<<<128, 256, 0, stream>>>(mixW, mixb, ws);
    k35_blend<<<2048, 256, 0, stream>>>(newh, ws, step);
    kstat<<<1, 1024, 0, stream>>>(ws, out);
    kred<<<256, 256, 0, stream>>>(ws);
    kpred<<<1, 256, 0, stream>>>(headW, headb, ws, out);
}